// Round 5
// baseline (386.914 us; speedup 1.0000x reference)
//
#include <hip/hip_runtime.h>
#include <math.h>

#define BB 8
#define NN 4096
#define DD 768
#define EE 8
#define SS 2
#define ES 16
#define FF 3072  // 4*D

// ws layout (floats) — NO atomics anywhere, no zero-init needed:
//   A      @ 0        6291456  xspart[8][64][16][768]; reused as
//                              hpart[8][128][3072] then yspart[32][128][768]
//   logits @ 6291456  524288
//   xs     @ 6815744  98304
//   h      @ 6914048  393216
//   ys     @ 7307264  98304
//   mpart  @ 7405568  4096
//   spart  @ 7409664  4096
//   cmax   @ 7413760  128
//   cinv   @ 7413888  128
// total 7414016 floats = 29.7 MB

// ---------------------------------------------------------------------------
// K1 (NEW, fused): logits + slot-softmax + xs-partial accumulation.
// grid 512 = b(8) x grp(64); block 512 = 8 waves; 64 tokens/block (2 tiles
// of 32). x read ONCE, coalesced, staged in LDS [32][768] (98 KB).
// Logits: lane owns (slot j = lane&15, 24-d window); phi col in 24 regs;
//   x from LDS = 4 distinct addrs + 16-lane broadcast (conflict-free);
//   uu-reduce via shfl_xor(16,32), wave-reduce via part[8][32][16] LDS.
// Softmax on 16-lane groups -> dsp[32][16] LDS (disp never goes global).
// xs phase: waves {0,1,2}=slots 0-7, {4,5,6}=slots 8-15, d-per-lane
//   contiguous ds_read_b128; dsp read is wave-uniform broadcast.
// One coalesced xspart[b][grp][16][768] float4 store per block.
// ---------------------------------------------------------------------------
__global__ __launch_bounds__(512) void k_fused(const float* __restrict__ x,
                                               const float* __restrict__ phi,
                                               float* __restrict__ logits,
                                               float* __restrict__ xspart) {
  __shared__ float xt[32 * 768];       // 98304 B
  __shared__ float part[8][32][16];    // 16384 B
  __shared__ float dsp[32][16];        // 2048 B

  const int tid  = threadIdx.x;
  const int b    = blockIdx.x >> 6;
  const int grp  = blockIdx.x & 63;
  const int n0   = grp * 64;
  const int w    = tid >> 6;           // wave 0..7
  const int lane = tid & 63;
  const int j    = lane & 15;          // slot (logits phase)
  const int uu   = lane >> 4;          // d-subwindow 0..3
  const int d0   = 96 * w + 24 * uu;   // lane's 24-d window
  const int g    = w >> 2;             // xs phase: slot half
  const int wsub = w & 3;
  const bool xact = (wsub < 3);        // waves 3,7 idle in xs phase
  const int d4   = wsub * 64 + lane;   // xs phase: float4 column 0..191

  // phi column j over this lane's 24-d window -> registers (once per kernel)
  float preg[24];
  #pragma unroll
  for (int k = 0; k < 24; ++k) preg[k] = phi[(d0 + k) * ES + j];

  float4 acc[8];
  #pragma unroll
  for (int i = 0; i < 8; ++i) acc[i] = make_float4(0.f, 0.f, 0.f, 0.f);

  for (int tile = 0; tile < 2; ++tile) {
    const int nt = n0 + tile * 32;

    // ---- stage x tile: 6144 float4, 12 per thread, coalesced ----
    #pragma unroll
    for (int i = 0; i < 12; ++i) {
      const int f4 = tid + i * 512;
      const int r  = f4 / 192, c = f4 % 192;
      *(float4*)(xt + r * 768 + 4 * c) =
          *(const float4*)(x + ((size_t)(b * NN + nt + r)) * DD + 4 * c);
    }
    __syncthreads();

    // ---- logits partials: all 8 waves, all 32 tokens ----
    for (int t = 0; t < 32; ++t) {
      float p = 0.f;
      #pragma unroll
      for (int i4 = 0; i4 < 6; ++i4) {
        const float4 xv = *(const float4*)(xt + t * 768 + d0 + 4 * i4);
        p += xv.x * preg[4 * i4] + xv.y * preg[4 * i4 + 1] +
             xv.z * preg[4 * i4 + 2] + xv.w * preg[4 * i4 + 3];
      }
      p += __shfl_xor(p, 16);   // reduce over uu
      p += __shfl_xor(p, 32);
      if (uu == 0) part[w][t][j] = p;
    }
    __syncthreads();

    // ---- wave-reduce + slot-softmax; thread (t = tid>>4, jj = tid&15) ----
    {
      const int t = tid >> 4, jj = tid & 15;
      float s = 0.f;
      #pragma unroll
      for (int ww = 0; ww < 8; ++ww) s += part[ww][t][jj];
      float m = s;
      m = fmaxf(m, __shfl_xor(m, 1));
      m = fmaxf(m, __shfl_xor(m, 2));
      m = fmaxf(m, __shfl_xor(m, 4));
      m = fmaxf(m, __shfl_xor(m, 8));
      const float ev = __expf(s - m);
      float sum = ev;
      sum += __shfl_xor(sum, 1);
      sum += __shfl_xor(sum, 2);
      sum += __shfl_xor(sum, 4);
      sum += __shfl_xor(sum, 8);
      logits[((size_t)(b * NN + nt + t)) * ES + jj] = s;   // coalesced
      dsp[t][jj] = ev * (1.f / sum);
    }
    __syncthreads();

    // ---- xs accumulate: 6 active waves, d-per-lane ----
    if (xact) {
      for (int t = 0; t < 32; ++t) {
        const float4 xv = *(const float4*)(xt + t * 768 + 4 * d4);
        #pragma unroll
        for (int i = 0; i < 8; ++i) {
          const float dw = dsp[t][8 * g + i];   // wave-uniform broadcast
          acc[i].x += dw * xv.x; acc[i].y += dw * xv.y;
          acc[i].z += dw * xv.z; acc[i].w += dw * xv.w;
        }
      }
    }
    __syncthreads();   // xt about to be overwritten by next tile
  }

  if (xact) {
    #pragma unroll
    for (int i = 0; i < 8; ++i)
      *(float4*)(xspart + (((size_t)(b * 64 + grp)) * 16 + 8 * g + i) * DD +
                 4 * d4) = acc[i];
  }
}

// ---------------------------------------------------------------------------
// K2a: per-chunk combine-softmax partials (unchanged)
// ---------------------------------------------------------------------------
__global__ __launch_bounds__(128) void k_cpart(const float* __restrict__ logits,
                                               float* __restrict__ mpart,
                                               float* __restrict__ spart) {
  __shared__ float4 red[128][4];
  const int b   = blockIdx.x >> 5;
  const int ch  = blockIdx.x & 31;
  const int tid = threadIdx.x;
  const size_t base = (size_t)(b * NN + ch * 128 + tid) * ES;

  float4 v[4];
  #pragma unroll
  for (int q = 0; q < 4; ++q) v[q] = *(const float4*)(logits + base + 4 * q);
  #pragma unroll
  for (int q = 0; q < 4; ++q) red[tid][q] = v[q];
  __syncthreads();
  for (int s = 64; s > 0; s >>= 1) {
    if (tid < s) {
      #pragma unroll
      for (int q = 0; q < 4; ++q) {
        float4 a = red[tid][q], o = red[tid + s][q];
        a.x = fmaxf(a.x, o.x); a.y = fmaxf(a.y, o.y);
        a.z = fmaxf(a.z, o.z); a.w = fmaxf(a.w, o.w);
        red[tid][q] = a;
      }
    }
    __syncthreads();
  }
  float4 mx[4];
  #pragma unroll
  for (int q = 0; q < 4; ++q) mx[q] = red[0][q];
  __syncthreads();

  #pragma unroll
  for (int q = 0; q < 4; ++q)
    red[tid][q] = make_float4(__expf(v[q].x - mx[q].x), __expf(v[q].y - mx[q].y),
                              __expf(v[q].z - mx[q].z), __expf(v[q].w - mx[q].w));
  __syncthreads();
  for (int s = 64; s > 0; s >>= 1) {
    if (tid < s) {
      #pragma unroll
      for (int q = 0; q < 4; ++q) {
        float4 a = red[tid][q], o = red[tid + s][q];
        a.x += o.x; a.y += o.y; a.z += o.z; a.w += o.w;
        red[tid][q] = a;
      }
    }
    __syncthreads();
  }
  if (tid == 0) {
    const int ob = (b * 32 + ch) * ES;
    #pragma unroll
    for (int q = 0; q < 4; ++q) {
      *(float4*)(mpart + ob + 4 * q) = mx[q];
      *(float4*)(spart + ob + 4 * q) = red[0][q];
    }
  }
}

// ---------------------------------------------------------------------------
// K2b: global combine stats (unchanged)
// ---------------------------------------------------------------------------
__global__ __launch_bounds__(64) void k_cfin(const float* __restrict__ mpart,
                                             const float* __restrict__ spart,
                                             float* __restrict__ cmax,
                                             float* __restrict__ cinv) {
  const int b = blockIdx.x;
  const int j = threadIdx.x;
  if (j < 16) {
    float m = -1e30f;
    #pragma unroll 4
    for (int c = 0; c < 32; ++c)
      m = fmaxf(m, mpart[(b * 32 + c) * ES + j]);
    float S = 0.f;
    #pragma unroll 4
    for (int c = 0; c < 32; ++c)
      S += spart[(b * 32 + c) * ES + j] * __expf(mpart[(b * 32 + c) * ES + j] - m);
    cmax[b * ES + j] = m;
    cinv[b * ES + j] = 1.f / S;
  }
}

// ---------------------------------------------------------------------------
// K3b: xs[b][es][d] = sum_p xspart[b][p][es][d]   (unchanged)
// ---------------------------------------------------------------------------
__global__ __launch_bounds__(256) void k_xsB(const float* __restrict__ xspart,
                                             float* __restrict__ xs) {
  const int q4  = blockIdx.x * 256 + threadIdx.x;  // [0, 24576)
  const int row = q4 / 192;                        // b*16+es
  const int c4  = q4 % 192;
  const int b   = row >> 4;
  const int e   = row & 15;
  float4 s = make_float4(0.f, 0.f, 0.f, 0.f);
  #pragma unroll 8
  for (int p = 0; p < 64; ++p) {
    const float4 v =
        *(const float4*)(xspart + (((size_t)(b * 64 + p)) * 16 + e) * DD + 4 * c4);
    s.x += v.x; s.y += v.y; s.z += v.z; s.w += v.w;
  }
  *(float4*)(xs + (size_t)row * DD + 4 * c4) = s;
}

// ---------------------------------------------------------------------------
// K4: hpart[dp][e*16+r][f] = xs_row(r) @ w1[e][d-chunk]   (unchanged)
// ---------------------------------------------------------------------------
__global__ __launch_bounds__(256) void k_ffn1(const float* __restrict__ xs,
                                              const float* __restrict__ w1,
                                              float* __restrict__ hpart) {
  const int bid  = blockIdx.x;
  const int e    = bid / 96;
  const int fblk = (bid / 8) % 12;
  const int dp   = bid % 8;
  const int tid  = threadIdx.x;
  const int f    = fblk * 256 + 4 * (tid & 63);
  const int sg   = __builtin_amdgcn_readfirstlane(tid >> 6);

  const float* xr[4];
  #pragma unroll
  for (int i = 0; i < 4; ++i) {
    const int r = 4 * sg + i;
    xr[i] = xs + (size_t)((r >> 1) * ES + e * SS + (r & 1)) * DD + dp * 96;
  }
  const float* wp = w1 + (size_t)e * DD * FF + (size_t)(dp * 96) * FF + f;

  float4 acc[4];
  #pragma unroll
  for (int i = 0; i < 4; ++i) acc[i] = make_float4(0.f, 0.f, 0.f, 0.f);

  #pragma unroll 4
  for (int dd = 0; dd < 96; ++dd) {
    const float4 wv = *(const float4*)(wp + (size_t)dd * FF);
    #pragma unroll
    for (int i = 0; i < 4; ++i) {
      const float xv = xr[i][dd];   // uniform -> SGPR
      acc[i].x += xv * wv.x; acc[i].y += xv * wv.y;
      acc[i].z += xv * wv.z; acc[i].w += xv * wv.w;
    }
  }
  #pragma unroll
  for (int i = 0; i < 4; ++i)
    *(float4*)(hpart + ((size_t)dp * 128 + e * 16 + 4 * sg + i) * FF + f) = acc[i];
}

// ---------------------------------------------------------------------------
// K4b: h = gelu_exact(sum_dp hpart + b1)   (unchanged)
// ---------------------------------------------------------------------------
__global__ __launch_bounds__(256) void k_gelu(const float* __restrict__ hpart,
                                              const float* __restrict__ b1,
                                              float* __restrict__ h) {
  const int q4  = blockIdx.x * 256 + threadIdx.x;  // [0, 98304)
  const int row = q4 / 768;                        // e*16+r
  const int c4  = q4 % 768;
  const int e   = row >> 4;
  float4 s = make_float4(0.f, 0.f, 0.f, 0.f);
  #pragma unroll
  for (int dp = 0; dp < 8; ++dp) {
    const float4 v = *(const float4*)(hpart + ((size_t)dp * 128 + row) * FF + 4 * c4);
    s.x += v.x; s.y += v.y; s.z += v.z; s.w += v.w;
  }
  const float4 bb = *(const float4*)(b1 + e * FF + 4 * c4);
  const float ks = 0.70710678118654752f;
  float a;
  float4 o;
  a = s.x + bb.x; o.x = 0.5f * a * (1.f + erff(a * ks));
  a = s.y + bb.y; o.y = 0.5f * a * (1.f + erff(a * ks));
  a = s.z + bb.z; o.z = 0.5f * a * (1.f + erff(a * ks));
  a = s.w + bb.w; o.w = 0.5f * a * (1.f + erff(a * ks));
  *(float4*)(h + (size_t)row * FF + 4 * c4) = o;
}

// ---------------------------------------------------------------------------
// K5: yspart[fp][e*16+r][d] = h_row(r) @ w2[e][f-chunk]   (unchanged)
// ---------------------------------------------------------------------------
__global__ __launch_bounds__(256) void k_ffn2(const float* __restrict__ h,
                                              const float* __restrict__ w2,
                                              float* __restrict__ yspart) {
  const int bid  = blockIdx.x;
  const int e    = bid / 96;
  const int dblk = (bid / 32) % 3;
  const int fp   = bid % 32;
  const int tid  = threadIdx.x;
  const int dcol = dblk * 256 + 4 * (tid & 63);
  const int sg   = __builtin_amdgcn_readfirstlane(tid >> 6);
  const int f0   = fp * 96;

  const float* hr[4];
  #pragma unroll
  for (int i = 0; i < 4; ++i)
    hr[i] = h + (size_t)(e * 16 + 4 * sg + i) * FF + f0;
  const float* wp = w2 + (size_t)e * FF * DD + (size_t)f0 * DD + dcol;

  float4 acc[4];
  #pragma unroll
  for (int i = 0; i < 4; ++i) acc[i] = make_float4(0.f, 0.f, 0.f, 0.f);

  #pragma unroll 4
  for (int ff = 0; ff < 96; ++ff) {
    const float4 wv = *(const float4*)(wp + (size_t)ff * DD);
    #pragma unroll
    for (int i = 0; i < 4; ++i) {
      const float hv = hr[i][ff];   // uniform -> SGPR
      acc[i].x += hv * wv.x; acc[i].y += hv * wv.y;
      acc[i].z += hv * wv.z; acc[i].w += hv * wv.w;
    }
  }
  #pragma unroll
  for (int i = 0; i < 4; ++i)
    *(float4*)(yspart + ((size_t)fp * 128 + e * 16 + 4 * sg + i) * DD + dcol) = acc[i];
}

// ---------------------------------------------------------------------------
// K5b: ys = sum_fp yspart + b2   (unchanged)
// ---------------------------------------------------------------------------
__global__ __launch_bounds__(256) void k_ysred(const float* __restrict__ yspart,
                                               const float* __restrict__ b2,
                                               float* __restrict__ ys) {
  const int q4  = blockIdx.x * 256 + threadIdx.x;  // [0, 24576)
  const int q   = q4 / 192;                        // b*16+es
  const int c4  = q4 % 192;
  const int b   = q >> 4;
  const int es  = q & 15;
  const int e   = es >> 1;
  const int s   = es & 1;
  const int prow = e * 16 + b * 2 + s;
  float4 acc = *(const float4*)(b2 + e * DD + 4 * c4);
  #pragma unroll 8
  for (int fp = 0; fp < 32; ++fp) {
    const float4 v = *(const float4*)(yspart + ((size_t)fp * 128 + prow) * DD + 4 * c4);
    acc.x += v.x; acc.y += v.y; acc.z += v.z; acc.w += v.w;
  }
  *(float4*)(ys + (size_t)q * DD + 4 * c4) = acc;
}

// ---------------------------------------------------------------------------
// K6: y = sum_es exp(logits-cmax)*cinv * ys   (unchanged)
// ---------------------------------------------------------------------------
__global__ __launch_bounds__(192) void k_combine(const float* __restrict__ logits,
                                                 const float* __restrict__ ys,
                                                 const float* __restrict__ cmax,
                                                 const float* __restrict__ cinv,
                                                 float* __restrict__ y) {
  const int b   = blockIdx.x >> 6;
  const int n0  = (blockIdx.x & 63) * 64;
  const int tid = threadIdx.x;

  float4 ysr[16];
  float cm[16], ci[16];
  #pragma unroll
  for (int es = 0; es < 16; ++es) {
    cm[es] = cmax[b * ES + es];   // uniform -> SGPR
    ci[es] = cinv[b * ES + es];
    ysr[es] = *(const float4*)(ys + (size_t)(b * ES + es) * DD + 4 * tid);
  }
  #pragma unroll 2
  for (int t = 0; t < 64; ++t) {
    const size_t tb = (size_t)(b * NN + n0 + t);
    const float* lp = logits + tb * ES;   // uniform -> scalar loads
    float4 a = make_float4(0.f, 0.f, 0.f, 0.f);
    #pragma unroll
    for (int es = 0; es < 16; ++es) {
      const float c = __expf(lp[es] - cm[es]) * ci[es];
      a.x += c * ysr[es].x; a.y += c * ysr[es].y;
      a.z += c * ysr[es].z; a.w += c * ysr[es].w;
    }
    *(float4*)(y + tb * DD + 4 * tid) = a;
  }
}

extern "C" void kernel_launch(void* const* d_in, const int* in_sizes, int n_in,
                              void* d_out, int out_size, void* d_ws, size_t ws_size,
                              hipStream_t stream) {
  const float* x   = (const float*)d_in[0];
  const float* phi = (const float*)d_in[1];
  const float* w1  = (const float*)d_in[2];
  const float* b1  = (const float*)d_in[3];
  const float* w2  = (const float*)d_in[4];
  const float* b2  = (const float*)d_in[5];
  float* y  = (float*)d_out;
  float* ws = (float*)d_ws;

  float* A      = ws;                // 6291456: xspart / hpart / yspart (reused)
  float* logits = ws + 6291456;      // 524288
  float* xs     = ws + 6815744;      // 98304
  float* h      = ws + 6914048;      // 393216
  float* ys     = ws + 7307264;      // 98304
  float* mpart  = ws + 7405568;      // 4096
  float* spart  = ws + 7409664;      // 4096
  float* cmax   = ws + 7413760;      // 128
  float* cinv   = ws + 7413888;      // 128

  hipLaunchKernelGGL(k_fused,   dim3(512), dim3(512), 0, stream, x, phi, logits, A);
  hipLaunchKernelGGL(k_cpart,   dim3(256), dim3(128), 0, stream, logits, mpart, spart);
  hipLaunchKernelGGL(k_cfin,    dim3(8),   dim3(64),  0, stream, mpart, spart, cmax, cinv);
  hipLaunchKernelGGL(k_xsB,     dim3(96),  dim3(256), 0, stream, A, xs);
  hipLaunchKernelGGL(k_ffn1,    dim3(768), dim3(256), 0, stream, xs, w1, A);
  hipLaunchKernelGGL(k_gelu,    dim3(384), dim3(256), 0, stream, A, b1, h);
  hipLaunchKernelGGL(k_ffn2,    dim3(768), dim3(256), 0, stream, h, w2, A);
  hipLaunchKernelGGL(k_ysred,   dim3(96),  dim3(256), 0, stream, A, b2, ys);
  hipLaunchKernelGGL(k_combine, dim3(512), dim3(192), 0, stream, logits, ys, cmax, cinv, y);
}

// Round 6
// 362.834 us; speedup vs baseline: 1.0664x; 1.0664x over previous
//
#include <hip/hip_runtime.h>
#include <math.h>

#define BB 8
#define NN 4096
#define DD 768
#define EE 8
#define SS 2
#define ES 16
#define FF 3072  // 4*D

// ws layout (floats) — NO atomics anywhere, no zero-init needed:
//   A      @ 0        6291456  xspart[8][64][16][768]; reused as
//                              hpart[16][128][3072] then yspart[64][128][768]
//                              (each exactly 6291456 floats)
//   logits @ 6291456  524288
//   xs     @ 6815744  98304
//   h      @ 6914048  393216
//   ys     @ 7307264  98304
//   mpart  @ 7405568  4096
//   spart  @ 7409664  4096
//   cmax   @ 7413760  128
//   cinv   @ 7413888  128
// total 7414016 floats = 29.7 MB

// ---------------------------------------------------------------------------
// K1 (fused): logits + slot-softmax + xs-partial accumulation.
// grid 512 = b(8) x grp(64); block 512 = 8 waves; 64 tokens/block in
// FOUR 16-token tiles (was two 32-token tiles).
// LDS: xt 48K + part 8K + dsp 1K = 57 KB -> 2 blocks/CU (16 waves, was 8).
// ---------------------------------------------------------------------------
__global__ __launch_bounds__(512) void k_fused(const float* __restrict__ x,
                                               const float* __restrict__ phi,
                                               float* __restrict__ logits,
                                               float* __restrict__ xspart) {
  __shared__ float xt[16 * 768];       // 49152 B
  __shared__ float part[8][16][16];    //  8192 B
  __shared__ float dsp[16][16];        //  1024 B

  const int tid  = threadIdx.x;
  const int b    = blockIdx.x >> 6;
  const int grp  = blockIdx.x & 63;
  const int n0   = grp * 64;
  const int w    = tid >> 6;           // wave 0..7
  const int lane = tid & 63;
  const int j    = lane & 15;          // slot (logits phase)
  const int uu   = lane >> 4;          // d-subwindow 0..3
  const int d0   = 96 * w + 24 * uu;   // lane's 24-d window
  const int g    = w >> 2;             // xs phase: slot half
  const int wsub = w & 3;
  const bool xact = (wsub < 3);        // waves 3,7 idle in xs phase
  const int d4   = wsub * 64 + lane;   // xs phase: float4 column 0..191

  // phi column j over this lane's 24-d window -> registers (once)
  float preg[24];
  #pragma unroll
  for (int k = 0; k < 24; ++k) preg[k] = phi[(d0 + k) * ES + j];

  float4 acc[8];
  #pragma unroll
  for (int i = 0; i < 8; ++i) acc[i] = make_float4(0.f, 0.f, 0.f, 0.f);

  for (int tile = 0; tile < 4; ++tile) {
    const int nt = n0 + tile * 16;

    // ---- stage x tile: 3072 float4 (one contiguous 48 KB span), 6/thread --
    #pragma unroll
    for (int i = 0; i < 6; ++i) {
      const int f4 = tid + i * 512;
      *(float4*)(xt + 4 * f4) =
          *(const float4*)(x + ((size_t)(b * NN + nt)) * DD + 4 * f4);
    }
    __syncthreads();

    // ---- logits partials: all 8 waves, 16 tokens ----
    #pragma unroll 2
    for (int t = 0; t < 16; ++t) {
      float p = 0.f;
      #pragma unroll
      for (int i4 = 0; i4 < 6; ++i4) {
        const float4 xv = *(const float4*)(xt + t * 768 + d0 + 4 * i4);
        p += xv.x * preg[4 * i4] + xv.y * preg[4 * i4 + 1] +
             xv.z * preg[4 * i4 + 2] + xv.w * preg[4 * i4 + 3];
      }
      p += __shfl_xor(p, 16);   // reduce over uu
      p += __shfl_xor(p, 32);
      if (uu == 0) part[w][t][j] = p;
    }
    __syncthreads();

    // ---- wave-reduce + slot-softmax; threads 0..255: (t=tid>>4, jj=tid&15) -
    if (tid < 256) {
      const int t = tid >> 4, jj = tid & 15;
      float s = 0.f;
      #pragma unroll
      for (int ww = 0; ww < 8; ++ww) s += part[ww][t][jj];
      float m = s;
      m = fmaxf(m, __shfl_xor(m, 1));
      m = fmaxf(m, __shfl_xor(m, 2));
      m = fmaxf(m, __shfl_xor(m, 4));
      m = fmaxf(m, __shfl_xor(m, 8));
      const float ev = __expf(s - m);
      float sum = ev;
      sum += __shfl_xor(sum, 1);
      sum += __shfl_xor(sum, 2);
      sum += __shfl_xor(sum, 4);
      sum += __shfl_xor(sum, 8);
      logits[((size_t)(b * NN + nt + t)) * ES + jj] = s;   // coalesced
      dsp[t][jj] = ev * (1.f / sum);
    }
    __syncthreads();

    // ---- xs accumulate: 6 active waves, d-per-lane ----
    if (xact) {
      #pragma unroll 2
      for (int t = 0; t < 16; ++t) {
        const float4 xv = *(const float4*)(xt + t * 768 + 4 * d4);
        #pragma unroll
        for (int i = 0; i < 8; ++i) {
          const float dw = dsp[t][8 * g + i];   // wave-uniform broadcast
          acc[i].x += dw * xv.x; acc[i].y += dw * xv.y;
          acc[i].z += dw * xv.z; acc[i].w += dw * xv.w;
        }
      }
    }
    __syncthreads();   // xt about to be overwritten by next tile
  }

  if (xact) {
    #pragma unroll
    for (int i = 0; i < 8; ++i)
      *(float4*)(xspart + (((size_t)(b * 64 + grp)) * 16 + 8 * g + i) * DD +
                 4 * d4) = acc[i];
  }
}

// ---------------------------------------------------------------------------
// K2a: per-chunk combine-softmax partials (unchanged)
// ---------------------------------------------------------------------------
__global__ __launch_bounds__(128) void k_cpart(const float* __restrict__ logits,
                                               float* __restrict__ mpart,
                                               float* __restrict__ spart) {
  __shared__ float4 red[128][4];
  const int b   = blockIdx.x >> 5;
  const int ch  = blockIdx.x & 31;
  const int tid = threadIdx.x;
  const size_t base = (size_t)(b * NN + ch * 128 + tid) * ES;

  float4 v[4];
  #pragma unroll
  for (int q = 0; q < 4; ++q) v[q] = *(const float4*)(logits + base + 4 * q);
  #pragma unroll
  for (int q = 0; q < 4; ++q) red[tid][q] = v[q];
  __syncthreads();
  for (int s = 64; s > 0; s >>= 1) {
    if (tid < s) {
      #pragma unroll
      for (int q = 0; q < 4; ++q) {
        float4 a = red[tid][q], o = red[tid + s][q];
        a.x = fmaxf(a.x, o.x); a.y = fmaxf(a.y, o.y);
        a.z = fmaxf(a.z, o.z); a.w = fmaxf(a.w, o.w);
        red[tid][q] = a;
      }
    }
    __syncthreads();
  }
  float4 mx[4];
  #pragma unroll
  for (int q = 0; q < 4; ++q) mx[q] = red[0][q];
  __syncthreads();

  #pragma unroll
  for (int q = 0; q < 4; ++q)
    red[tid][q] = make_float4(__expf(v[q].x - mx[q].x), __expf(v[q].y - mx[q].y),
                              __expf(v[q].z - mx[q].z), __expf(v[q].w - mx[q].w));
  __syncthreads();
  for (int s = 64; s > 0; s >>= 1) {
    if (tid < s) {
      #pragma unroll
      for (int q = 0; q < 4; ++q) {
        float4 a = red[tid][q], o = red[tid + s][q];
        a.x += o.x; a.y += o.y; a.z += o.z; a.w += o.w;
        red[tid][q] = a;
      }
    }
    __syncthreads();
  }
  if (tid == 0) {
    const int ob = (b * 32 + ch) * ES;
    #pragma unroll
    for (int q = 0; q < 4; ++q) {
      *(float4*)(mpart + ob + 4 * q) = mx[q];
      *(float4*)(spart + ob + 4 * q) = red[0][q];
    }
  }
}

// ---------------------------------------------------------------------------
// K2b: global combine stats (unchanged)
// ---------------------------------------------------------------------------
__global__ __launch_bounds__(64) void k_cfin(const float* __restrict__ mpart,
                                             const float* __restrict__ spart,
                                             float* __restrict__ cmax,
                                             float* __restrict__ cinv) {
  const int b = blockIdx.x;
  const int j = threadIdx.x;
  if (j < 16) {
    float m = -1e30f;
    #pragma unroll 4
    for (int c = 0; c < 32; ++c)
      m = fmaxf(m, mpart[(b * 32 + c) * ES + j]);
    float S = 0.f;
    #pragma unroll 4
    for (int c = 0; c < 32; ++c)
      S += spart[(b * 32 + c) * ES + j] * __expf(mpart[(b * 32 + c) * ES + j] - m);
    cmax[b * ES + j] = m;
    cinv[b * ES + j] = 1.f / S;
  }
}

// ---------------------------------------------------------------------------
// K3b: xs[b][es][d] = sum_p xspart[b][p][es][d]   (unchanged)
// ---------------------------------------------------------------------------
__global__ __launch_bounds__(256) void k_xsB(const float* __restrict__ xspart,
                                             float* __restrict__ xs) {
  const int q4  = blockIdx.x * 256 + threadIdx.x;  // [0, 24576)
  const int row = q4 / 192;                        // b*16+es
  const int c4  = q4 % 192;
  const int b   = row >> 4;
  const int e   = row & 15;
  float4 s = make_float4(0.f, 0.f, 0.f, 0.f);
  #pragma unroll 8
  for (int p = 0; p < 64; ++p) {
    const float4 v =
        *(const float4*)(xspart + (((size_t)(b * 64 + p)) * 16 + e) * DD + 4 * c4);
    s.x += v.x; s.y += v.y; s.z += v.z; s.w += v.w;
  }
  *(float4*)(xs + (size_t)row * DD + 4 * c4) = s;
}

// ---------------------------------------------------------------------------
// K4: hpart[dp][e*16+r][f] = xs_row(r) @ w1[e][48-d chunk]
// grid 1536 = e(8) x fblk(12) x dp(16)  -> 6 blocks/CU (was 3).
// ---------------------------------------------------------------------------
__global__ __launch_bounds__(256) void k_ffn1(const float* __restrict__ xs,
                                              const float* __restrict__ w1,
                                              float* __restrict__ hpart) {
  const int bid  = blockIdx.x;
  const int e    = bid / 192;
  const int rem  = bid % 192;
  const int fblk = rem / 16;
  const int dp   = rem % 16;
  const int tid  = threadIdx.x;
  const int f    = fblk * 256 + 4 * (tid & 63);
  const int sg   = __builtin_amdgcn_readfirstlane(tid >> 6);

  const float* xr[4];
  #pragma unroll
  for (int i = 0; i < 4; ++i) {
    const int r = 4 * sg + i;
    xr[i] = xs + (size_t)((r >> 1) * ES + e * SS + (r & 1)) * DD + dp * 48;
  }
  const float* wp = w1 + (size_t)e * DD * FF + (size_t)(dp * 48) * FF + f;

  float4 acc[4];
  #pragma unroll
  for (int i = 0; i < 4; ++i) acc[i] = make_float4(0.f, 0.f, 0.f, 0.f);

  #pragma unroll 4
  for (int dd = 0; dd < 48; ++dd) {
    const float4 wv = *(const float4*)(wp + (size_t)dd * FF);
    #pragma unroll
    for (int i = 0; i < 4; ++i) {
      const float xv = xr[i][dd];   // uniform -> SGPR
      acc[i].x += xv * wv.x; acc[i].y += xv * wv.y;
      acc[i].z += xv * wv.z; acc[i].w += xv * wv.w;
    }
  }
  #pragma unroll
  for (int i = 0; i < 4; ++i)
    *(float4*)(hpart + ((size_t)dp * 128 + e * 16 + 4 * sg + i) * FF + f) = acc[i];
}

// ---------------------------------------------------------------------------
// K4b: h = gelu_exact(sum_dp(16) hpart + b1)
// ---------------------------------------------------------------------------
__global__ __launch_bounds__(256) void k_gelu(const float* __restrict__ hpart,
                                              const float* __restrict__ b1,
                                              float* __restrict__ h) {
  const int q4  = blockIdx.x * 256 + threadIdx.x;  // [0, 98304)
  const int row = q4 / 768;                        // e*16+r
  const int c4  = q4 % 768;
  const int e   = row >> 4;
  float4 s = make_float4(0.f, 0.f, 0.f, 0.f);
  #pragma unroll
  for (int dp = 0; dp < 16; ++dp) {
    const float4 v = *(const float4*)(hpart + ((size_t)dp * 128 + row) * FF + 4 * c4);
    s.x += v.x; s.y += v.y; s.z += v.z; s.w += v.w;
  }
  const float4 bb = *(const float4*)(b1 + e * FF + 4 * c4);
  const float ks = 0.70710678118654752f;
  float a;
  float4 o;
  a = s.x + bb.x; o.x = 0.5f * a * (1.f + erff(a * ks));
  a = s.y + bb.y; o.y = 0.5f * a * (1.f + erff(a * ks));
  a = s.z + bb.z; o.z = 0.5f * a * (1.f + erff(a * ks));
  a = s.w + bb.w; o.w = 0.5f * a * (1.f + erff(a * ks));
  *(float4*)(h + (size_t)row * FF + 4 * c4) = o;
}

// ---------------------------------------------------------------------------
// K5: yspart[fp][e*16+r][d] = h_row(r) @ w2[e][48-f chunk]
// grid 1536 = e(8) x dblk(3) x fp(64)  -> 6 blocks/CU (was 3).
// ---------------------------------------------------------------------------
__global__ __launch_bounds__(256) void k_ffn2(const float* __restrict__ h,
                                              const float* __restrict__ w2,
                                              float* __restrict__ yspart) {
  const int bid  = blockIdx.x;
  const int e    = bid / 192;
  const int rem  = bid % 192;
  const int dblk = rem / 64;
  const int fp   = rem % 64;
  const int tid  = threadIdx.x;
  const int dcol = dblk * 256 + 4 * (tid & 63);
  const int sg   = __builtin_amdgcn_readfirstlane(tid >> 6);
  const int f0   = fp * 48;

  const float* hr[4];
  #pragma unroll
  for (int i = 0; i < 4; ++i)
    hr[i] = h + (size_t)(e * 16 + 4 * sg + i) * FF + f0;
  const float* wp = w2 + (size_t)e * FF * DD + (size_t)f0 * DD + dcol;

  float4 acc[4];
  #pragma unroll
  for (int i = 0; i < 4; ++i) acc[i] = make_float4(0.f, 0.f, 0.f, 0.f);

  #pragma unroll 4
  for (int ff = 0; ff < 48; ++ff) {
    const float4 wv = *(const float4*)(wp + (size_t)ff * DD);
    #pragma unroll
    for (int i = 0; i < 4; ++i) {
      const float hv = hr[i][ff];   // uniform -> SGPR
      acc[i].x += hv * wv.x; acc[i].y += hv * wv.y;
      acc[i].z += hv * wv.z; acc[i].w += hv * wv.w;
    }
  }
  #pragma unroll
  for (int i = 0; i < 4; ++i)
    *(float4*)(yspart + ((size_t)fp * 128 + e * 16 + 4 * sg + i) * DD + dcol) = acc[i];
}

// ---------------------------------------------------------------------------
// K5b: ys = sum_fp(64) yspart + b2
// ---------------------------------------------------------------------------
__global__ __launch_bounds__(256) void k_ysred(const float* __restrict__ yspart,
                                               const float* __restrict__ b2,
                                               float* __restrict__ ys) {
  const int q4  = blockIdx.x * 256 + threadIdx.x;  // [0, 24576)
  const int q   = q4 / 192;                        // b*16+es
  const int c4  = q4 % 192;
  const int b   = q >> 4;
  const int es  = q & 15;
  const int e   = es >> 1;
  const int s   = es & 1;
  const int prow = e * 16 + b * 2 + s;
  float4 acc = *(const float4*)(b2 + e * DD + 4 * c4);
  #pragma unroll 8
  for (int fp = 0; fp < 64; ++fp) {
    const float4 v = *(const float4*)(yspart + ((size_t)fp * 128 + prow) * DD + 4 * c4);
    acc.x += v.x; acc.y += v.y; acc.z += v.z; acc.w += v.w;
  }
  *(float4*)(ys + (size_t)q * DD + 4 * c4) = acc;
}

// ---------------------------------------------------------------------------
// K6: y = sum_es exp(logits-cmax)*cinv * ys
// grid 2048 = b(8) x tokgrp(256, 16 tokens each)  -> 8 blocks/CU (was 2).
// ---------------------------------------------------------------------------
__global__ __launch_bounds__(192) void k_combine(const float* __restrict__ logits,
                                                 const float* __restrict__ ys,
                                                 const float* __restrict__ cmax,
                                                 const float* __restrict__ cinv,
                                                 float* __restrict__ y) {
  const int b   = blockIdx.x >> 8;
  const int n0  = (blockIdx.x & 255) * 16;
  const int tid = threadIdx.x;

  float4 ysr[16];
  float cm[16], ci[16];
  #pragma unroll
  for (int es = 0; es < 16; ++es) {
    cm[es] = cmax[b * ES + es];   // uniform -> SGPR
    ci[es] = cinv[b * ES + es];
    ysr[es] = *(const float4*)(ys + (size_t)(b * ES + es) * DD + 4 * tid);
  }
  #pragma unroll 2
  for (int t = 0; t < 16; ++t) {
    const size_t tb = (size_t)(b * NN + n0 + t);
    const float* lp = logits + tb * ES;   // uniform -> scalar loads
    float4 a = make_float4(0.f, 0.f, 0.f, 0.f);
    #pragma unroll
    for (int es = 0; es < 16; ++es) {
      const float c = __expf(lp[es] - cm[es]) * ci[es];
      a.x += c * ysr[es].x; a.y += c * ysr[es].y;
      a.z += c * ysr[es].z; a.w += c * ysr[es].w;
    }
    *(float4*)(y + tb * DD + 4 * tid) = a;
  }
}

extern "C" void kernel_launch(void* const* d_in, const int* in_sizes, int n_in,
                              void* d_out, int out_size, void* d_ws, size_t ws_size,
                              hipStream_t stream) {
  const float* x   = (const float*)d_in[0];
  const float* phi = (const float*)d_in[1];
  const float* w1  = (const float*)d_in[2];
  const float* b1  = (const float*)d_in[3];
  const float* w2  = (const float*)d_in[4];
  const float* b2  = (const float*)d_in[5];
  float* y  = (float*)d_out;
  float* ws = (float*)d_ws;

  float* A      = ws;                // 6291456: xspart / hpart / yspart (reused)
  float* logits = ws + 6291456;      // 524288
  float* xs     = ws + 6815744;      // 98304
  float* h      = ws + 6914048;      // 393216
  float* ys     = ws + 7307264;      // 98304
  float* mpart  = ws + 7405568;      // 4096
  float* spart  = ws + 7409664;      // 4096
  float* cmax   = ws + 7413760;      // 128
  float* cinv   = ws + 7413888;      // 128

  hipLaunchKernelGGL(k_fused,   dim3(512),  dim3(512), 0, stream, x, phi, logits, A);
  hipLaunchKernelGGL(k_cpart,   dim3(256),  dim3(128), 0, stream, logits, mpart, spart);
  hipLaunchKernelGGL(k_cfin,    dim3(8),    dim3(64),  0, stream, mpart, spart, cmax, cinv);
  hipLaunchKernelGGL(k_xsB,     dim3(96),   dim3(256), 0, stream, A, xs);
  hipLaunchKernelGGL(k_ffn1,    dim3(1536), dim3(256), 0, stream, xs, w1, A);
  hipLaunchKernelGGL(k_gelu,    dim3(384),  dim3(256), 0, stream, A, b1, h);
  hipLaunchKernelGGL(k_ffn2,    dim3(1536), dim3(256), 0, stream, h, w2, A);
  hipLaunchKernelGGL(k_ysred,   dim3(96),   dim3(256), 0, stream, A, b2, ys);
  hipLaunchKernelGGL(k_combine, dim3(2048), dim3(192), 0, stream, logits, ys, cmax, cinv, y);
}